// Round 6
// baseline (45.082 us; speedup 1.0000x reference)
//
#include <hip/hip_runtime.h>

// B=524288 independent attentions over [S=10, D=6].
// out[b,q] = sum_k softmax_k(score[q,k]) * vsum[k]
// score[q,k] = t_q . x_k + a_k  (q-constant terms cancel in softmax).
// Precompute folds log2(e) into G and w so softmax exp is a bare v_exp_f32:
//   G'[d][dp] = log2e * sum_e Wq[e][d] Wk[e][dp]
//   w'[dp]    = log2e * sum_e bq[e]  Wk[e][dp]
//   vsum[k]   = wvs . x_k + bvs
// ws layout (floats): [0..35] G', [36..41] w', [42..47] wvs, [48] bvs
//
// R5 lesson: all three prior structures hit ~43 us = 3.4 TB/s (54% duty).
// Memory phases were bursty (drain at barrier, zero in-flight during compute).
// R6: double-buffered tiles, prefetch next tile before the compute loop, and
// coalesced stores via an LDS bounce (20B/lane strided stores were 2x write amp).

#define NB 524288
#define S 10
#define D 6
#define TPB 128
#define EPT 64                 // elements per tile (2 threads per element)
#define TILES 8                // tiles per block -> grid = NB/(EPT*TILES) = 1024
#define XFL (S * D)            // 60 floats per element
#define TFL (EPT * XFL)        // 3840 floats = 15360 B per tile buffer

__global__ void precompute_kernel(const float* __restrict__ Wk, const float* __restrict__ bk,
                                  const float* __restrict__ Wq, const float* __restrict__ bq,
                                  const float* __restrict__ Wv, const float* __restrict__ bv,
                                  float* __restrict__ ws) {
    const float LOG2E = 1.44269504088896340736f;
    int t = threadIdx.x;
    if (t < 36) {
        int d = t / 6, dp = t % 6;
        float g = 0.f;
        for (int e = 0; e < D; ++e) g += Wq[e * D + d] * Wk[e * D + dp];
        ws[t] = g * LOG2E;
    } else if (t < 42) {
        int dp = t - 36;
        float s = 0.f;
        for (int e = 0; e < D; ++e) s += bq[e] * Wk[e * D + dp];
        ws[t] = s * LOG2E;
    } else if (t < 48) {
        int d = t - 42;
        float s = 0.f;
        for (int e = 0; e < D; ++e) s += Wv[e * D + d];
        ws[t] = s;
    } else if (t == 48) {
        float s = 0.f;
        for (int e = 0; e < D; ++e) s += bv[e];
        ws[t] = s;
    }
}

__device__ __forceinline__ float sconst(const float* __restrict__ p, int i) {
    return __int_as_float(__builtin_amdgcn_readfirstlane(__float_as_int(p[i])));
}

// Stage one 15360 B tile: 15 chunks of 1 KB (64 lanes x 16 B), 2 waves.
__device__ __forceinline__ void stage_tile(const float* __restrict__ gsrc,
                                           float* __restrict__ ldst,
                                           int wave, int lane) {
    #pragma unroll
    for (int i = 0; i < 8; ++i) {
        int c = wave + 2 * i;
        if (c < 15) {
            __builtin_amdgcn_global_load_lds(
                (const __attribute__((address_space(1))) void*)(gsrc + c * 256 + lane * 4),
                (__attribute__((address_space(3))) void*)(ldst + c * 256 + lane * 4),
                16, 0, 0);
        }
    }
}

// (128,4): 128-VGPR budget. LDS 30720 B -> 5 blocks/CU (10 waves/CU).
__global__ __launch_bounds__(TPB, 4) void attn_kernel(const float* __restrict__ x,
                                                      const float* __restrict__ ws,
                                                      float* __restrict__ out) {
    __shared__ float xs[2][TFL];
    const int t = threadIdx.x;
    const int wave = t >> 6;
    const int lane = t & 63;
    const int blk = blockIdx.x;

    // Constants pinned to SGPRs.
    float G[36], w[6], wvs[6];
    #pragma unroll
    for (int i = 0; i < 36; ++i) G[i] = sconst(ws, i);
    #pragma unroll
    for (int i = 0; i < 6; ++i) w[i] = sconst(ws, 36 + i);
    #pragma unroll
    for (int i = 0; i < 6; ++i) wvs[i] = sconst(ws, 42 + i);
    const float bvs = sconst(ws, 48);

    const float* gbase = x + (size_t)blk * (TILES * TFL);
    stage_tile(gbase, &xs[0][0], wave, lane);   // tile 0 in flight

    #pragma unroll 2
    for (int tt = 0; tt < TILES; ++tt) {
        // Tile tt's loads complete here (compiler drains vmcnt before s_barrier);
        // also fences tile tt-1's out-staging reads of buffer (tt+1)&1.
        __syncthreads();

        const float* xe = &xs[tt & 1][(t >> 1) * XFL];

        // Bulk LDS->reg: 15 x ds_read_b128. Compile-time xv indices only (rule #20).
        float xv[XFL];
        const float4* xr = (const float4*)xe;
        #pragma unroll
        for (int i = 0; i < 15; ++i) {
            float4 v = xr[i];
            xv[4 * i + 0] = v.x;
            xv[4 * i + 1] = v.y;
            xv[4 * i + 2] = v.z;
            xv[4 * i + 3] = v.w;
        }

        // tq rows depend on runtime h=t&1 -> read via LDS (addr = t*30 + const,
        // lane stride 30 floats, gcd(30,32)=2 -> 2-way, free).
        const float* xq0 = xe + (t & 1) * (5 * D);
        float tq[5][6];
        #pragma unroll
        for (int j = 0; j < 5; ++j) {
            float xq[6];
            #pragma unroll
            for (int d = 0; d < 6; ++d) xq[d] = xq0[j * 6 + d];
            #pragma unroll
            for (int dp = 0; dp < 6; ++dp) {
                float s = 0.f;
                #pragma unroll
                for (int d = 0; d < 6; ++d) s += xq[d] * G[d * 6 + dp];
                tq[j][dp] = s;
            }
        }

        // Prefetch next tile into the other buffer; stays in flight under the
        // k-loop below (its previous readers were fenced at the top barrier).
        if (tt + 1 < TILES)
            stage_tile(gbase + (size_t)(tt + 1) * TFL, &xs[(tt + 1) & 1][0], wave, lane);

        // Pure register math: scores + softmax + weighted vsum.
        float num[5] = {0.f, 0.f, 0.f, 0.f, 0.f};
        float den[5] = {0.f, 0.f, 0.f, 0.f, 0.f};
        #pragma unroll
        for (int k = 0; k < S; ++k) {
            float a = 0.f, vk = bvs;
            #pragma unroll
            for (int d = 0; d < 6; ++d) {
                a += w[d] * xv[k * 6 + d];
                vk += wvs[d] * xv[k * 6 + d];
            }
            #pragma unroll
            for (int j = 0; j < 5; ++j) {
                float s = a;
                #pragma unroll
                for (int d = 0; d < 6; ++d) s += tq[j][d] * xv[k * 6 + d];
                float ex = __builtin_amdgcn_exp2f(s);
                den[j] += ex;
                num[j] += ex * vk;
            }
        }

        __syncthreads();   // all reads of xs[tt&1] done -> safe to overwrite with outs

        // Out bounce: lane t writes floats t*5..t*5+4 (gcd(5,32)=1, conflict-free).
        float* os = &xs[tt & 1][0];
        #pragma unroll
        for (int j = 0; j < 5; ++j)
            os[t * 5 + j] = num[j] * __builtin_amdgcn_rcpf(den[j]);

        __syncthreads();

        // Coalesced store: 640 floats = 5 rows of 128 consecutive dwords.
        float* ob = out + (size_t)(blk * TILES + tt) * (EPT * S);
        #pragma unroll
        for (int i = 0; i < 5; ++i)
            ob[i * TPB + t] = os[i * TPB + t];
    }
}

extern "C" void kernel_launch(void* const* d_in, const int* in_sizes, int n_in,
                              void* d_out, int out_size, void* d_ws, size_t ws_size,
                              hipStream_t stream) {
    const float* x  = (const float*)d_in[0];
    const float* Wk = (const float*)d_in[1];
    const float* bk = (const float*)d_in[2];
    const float* Wq = (const float*)d_in[3];
    const float* bq = (const float*)d_in[4];
    const float* Wv = (const float*)d_in[5];
    const float* bv = (const float*)d_in[6];
    float* out = (float*)d_out;
    float* ws  = (float*)d_ws;

    precompute_kernel<<<1, 64, 0, stream>>>(Wk, bk, Wq, bq, Wv, bv, ws);
    attn_kernel<<<NB / (EPT * TILES), TPB, 0, stream>>>(x, ws, out);
}